// Round 1
// baseline (1962.570 us; speedup 1.0000x reference)
//
#include <hip/hip_runtime.h>

#define B_ 128
#define T_ 20
#define V_ 10000
#define H_ 512
#define F_ 49

typedef unsigned short u16;
typedef __attribute__((ext_vector_type(8))) short short8;
typedef __attribute__((ext_vector_type(4))) float floatx4;

// fp32 -> bf16 round-to-nearest-even (manual, no API dependency)
__device__ inline u16 f2b(float v) {
    unsigned u = __builtin_bit_cast(unsigned, v);
    unsigned rounding = 0x7FFFu + ((u >> 16) & 1u);
    return (u16)((u + rounding) >> 16);
}
__device__ inline float b2f(u16 h) {
    unsigned u = ((unsigned)h) << 16;
    return __builtin_bit_cast(float, u);
}

// ---------------- transpose + convert: src[K,N] f32 -> dst[N,K] bf16 ----------------
__global__ __launch_bounds__(256) void transpose_cvt(const float* __restrict__ src,
                                                     u16* __restrict__ dst, int K, int N) {
    __shared__ float tile[32][33];
    int n0 = blockIdx.x * 32, k0 = blockIdx.y * 32;
    int tx = threadIdx.x, ty = threadIdx.y;   // 32 x 8
    #pragma unroll
    for (int i = 0; i < 32; i += 8) {
        int k = k0 + ty + i, n = n0 + tx;
        tile[ty + i][tx] = (k < K && n < N) ? src[(size_t)k * N + n] : 0.f;
    }
    __syncthreads();
    #pragma unroll
    for (int i = 0; i < 32; i += 8) {
        int n = n0 + ty + i, k = k0 + tx;
        if (n < N && k < K) dst[(size_t)n * K + k] = f2b(tile[tx][ty + i]);
    }
}

// ---------------- build X[t*B+b, 0:2H] = [emb[tok], gf[b]] as bf16 ----------------
__global__ __launch_bounds__(256) void build_x(const int* __restrict__ cap,
                                               const float* __restrict__ emb,
                                               const float* __restrict__ gf,
                                               u16* __restrict__ X) {
    int r = blockIdx.x;                 // r = t*128 + b
    int t = r / B_, b = r % B_;
    int tok = cap[b * T_ + t];
    for (int col = threadIdx.x; col < 2 * H_; col += 256) {
        float v = (col < H_) ? emb[(size_t)tok * H_ + col] : gf[(size_t)b * H_ + (col - H_)];
        X[(size_t)r * (2 * H_) + col] = f2b(v);
    }
}

// ---------------- feat[b,f,h] = area[b,h,f] as bf16 ----------------
__global__ __launch_bounds__(256) void feat_cvt(const float* __restrict__ area,
                                                u16* __restrict__ feat) {
    int idx = blockIdx.x * 256 + threadIdx.x;
    if (idx >= B_ * F_ * H_) return;
    int h = idx & (H_ - 1);
    int bf_ = idx >> 9;
    int f = bf_ % F_, b = bf_ / F_;
    feat[idx] = f2b(area[((size_t)b * H_ + h) * F_ + f]);
}

// ---------------- init h (bf16) and c (f32) ----------------
__global__ __launch_bounds__(256) void init_hc(const float* __restrict__ h0,
                                               const float* __restrict__ c0,
                                               u16* __restrict__ hbf, float* __restrict__ c) {
    int i = blockIdx.x * 256 + threadIdx.x;
    if (i < B_ * H_) { hbf[i] = f2b(h0[i]); c[i] = c0[i]; }
}

// ---------------- LSTM elementwise ----------------
__global__ __launch_bounds__(256) void lstm_ew(const float* __restrict__ gates,
                                               float* __restrict__ c, u16* __restrict__ hbf) {
    int idx = blockIdx.x * 256 + threadIdx.x;   // 65536
    int b = idx >> 9, j = idx & (H_ - 1);
    const float* g = gates + (size_t)b * 4 * H_;
    float gi = g[j], gf_ = g[H_ + j], gg = g[2 * H_ + j], go = g[3 * H_ + j];
    float si = 1.f / (1.f + __expf(-gi));
    float sf = 1.f / (1.f + __expf(-gf_));
    float so = 1.f / (1.f + __expf(-go));
    float cn = sf * c[idx] + si * tanhf(gg);
    c[idx] = cn;
    hbf[idx] = f2b(so * tanhf(cn));
}

// ---------------- attention: scores -> softmax -> attended; write Hcat row b*T+t ----------------
__global__ __launch_bounds__(256) void attention_k(const float* __restrict__ Vproj,
                                                   const float* __restrict__ ah,
                                                   const float* __restrict__ wo,
                                                   const float* __restrict__ area,
                                                   const u16* __restrict__ hbf,
                                                   u16* __restrict__ Hcat, int t) {
    int b = blockIdx.x;
    __shared__ float sc[F_];
    int wave = threadIdx.x >> 6, lane = threadIdx.x & 63;
    // phase 1: scores[f] = sum_h wo[h]*tanh(Vproj[b,f,h]+ah[b,h])
    for (int f = wave; f < F_; f += 4) {
        const float* vp = Vproj + ((size_t)b * F_ + f) * H_;
        float s = 0.f;
        for (int h = lane; h < H_; h += 64)
            s += wo[h] * tanhf(vp[h] + ah[(size_t)b * H_ + h]);
        #pragma unroll
        for (int off = 32; off; off >>= 1) s += __shfl_xor(s, off);
        if (lane == 0) sc[f] = s;
    }
    __syncthreads();
    // phase 2: softmax over 49 (wave 0)
    if (threadIdx.x < 64) {
        float v = (threadIdx.x < F_) ? sc[threadIdx.x] : -1e30f;
        float m = v;
        #pragma unroll
        for (int off = 32; off; off >>= 1) m = fmaxf(m, __shfl_xor(m, off));
        float e = (threadIdx.x < F_) ? __expf(v - m) : 0.f;
        float sum = e;
        #pragma unroll
        for (int off = 32; off; off >>= 1) sum += __shfl_xor(sum, off);
        if (threadIdx.x < F_) sc[threadIdx.x] = e / sum;
    }
    __syncthreads();
    // phase 3: attended[h] = sum_f area[b,h,f]*alpha[f]; write Hcat
    size_t row = (size_t)b * T_ + t;
    for (int h = threadIdx.x; h < H_; h += 256) {
        const float* ar = area + ((size_t)b * H_ + h) * F_;
        float acc = 0.f;
        #pragma unroll
        for (int f = 0; f < F_; ++f) acc += ar[f] * sc[f];
        Hcat[row * (2 * H_) + h] = hbf[(size_t)b * H_ + h];
        Hcat[row * (2 * H_) + H_ + h] = f2b(acc);
    }
}

// ---------------- generic bf16 MFMA GEMM: C[M,N] = A[M,K] @ Bt[N,K]^T (+bias +D) ----------------
// A row-major bf16, Bt row-major bf16 (pre-transposed B), C f32.
template <int BM, int BN>
__global__ __launch_bounds__(256) void gemm_bf16(const u16* __restrict__ A, int lda,
                                                 const u16* __restrict__ Bt, int ldb,
                                                 float* __restrict__ C, int ldc,
                                                 const float* __restrict__ D, int ldd,
                                                 const float* __restrict__ bias1,
                                                 const float* __restrict__ bias2,
                                                 int M, int N, int K) {
    constexpr int LDS_LD = 32 + 8;      // bf16 per row (+8 pad, keeps 16B align, spreads banks)
    __shared__ __align__(16) u16 As[BM * LDS_LD];
    __shared__ __align__(16) u16 Bs[BN * LDS_LD];
    const int tid = threadIdx.x;
    const int wave = tid >> 6, lane = tid & 63;
    constexpr int MSUB = BM / 32, NSUB = BN / 32;
    const int wm = (wave >> 1) * (BM / 2);
    const int wn = (wave & 1) * (BN / 2);
    const int m0 = blockIdx.x * BM;
    const int n0 = blockIdx.y * BN;

    floatx4 acc[MSUB][NSUB];
    #pragma unroll
    for (int i = 0; i < MSUB; ++i)
        #pragma unroll
        for (int j = 0; j < NSUB; ++j)
            acc[i][j] = floatx4{0.f, 0.f, 0.f, 0.f};

    const int lm = lane & 15;
    const int kq = (lane >> 4) * 8;     // k offset within 32-wide K tile

    for (int kt = 0; kt < K / 32; ++kt) {
        // stage A tile [BM x 32]
        #pragma unroll
        for (int i = 0; i < BM / 64; ++i) {
            int r = (tid >> 2) + i * 64;
            int s = (tid & 3) * 8;
            const u16* g = A + (size_t)(m0 + r) * lda + kt * 32 + s;
            *(uint4*)&As[r * LDS_LD + s] = *(const uint4*)g;
        }
        // stage B tile [BN x 32] with N guard
        #pragma unroll
        for (int i = 0; i < BN / 64; ++i) {
            int r = (tid >> 2) + i * 64;
            int s = (tid & 3) * 8;
            int n = n0 + r;
            uint4 v = uint4{0u, 0u, 0u, 0u};
            if (n < N) v = *(const uint4*)(Bt + (size_t)n * ldb + kt * 32 + s);
            *(uint4*)&Bs[r * LDS_LD + s] = v;
        }
        __syncthreads();
        short8 af[MSUB], bfr[NSUB];
        #pragma unroll
        for (int i = 0; i < MSUB; ++i)
            af[i] = *(const short8*)&As[(wm + i * 16 + lm) * LDS_LD + kq];
        #pragma unroll
        for (int j = 0; j < NSUB; ++j)
            bfr[j] = *(const short8*)&Bs[(wn + j * 16 + lm) * LDS_LD + kq];
        #pragma unroll
        for (int i = 0; i < MSUB; ++i)
            #pragma unroll
            for (int j = 0; j < NSUB; ++j)
                acc[i][j] = __builtin_amdgcn_mfma_f32_16x16x32_bf16(af[i], bfr[j], acc[i][j], 0, 0, 0);
        __syncthreads();
    }

    // epilogue: C = acc (+bias1[col]) (+bias2[col]) (+D[row,col])
    #pragma unroll
    for (int i = 0; i < MSUB; ++i) {
        #pragma unroll
        for (int j = 0; j < NSUB; ++j) {
            #pragma unroll
            for (int r = 0; r < 4; ++r) {
                int row = m0 + wm + i * 16 + (lane >> 4) * 4 + r;
                int col = n0 + wn + j * 16 + lm;
                if (col < N) {
                    float v = acc[i][j][r];
                    if (bias1) v += bias1[col];
                    if (bias2) v += bias2[col];
                    if (D) v += D[(size_t)row * ldd + col];
                    C[(size_t)row * ldc + col] = v;
                }
            }
        }
    }
}

extern "C" void kernel_launch(void* const* d_in, const int* in_sizes, int n_in,
                              void* d_out, int out_size, void* d_ws, size_t ws_size,
                              hipStream_t stream) {
    const int*   cap   = (const int*)d_in[0];
    const float* gf    = (const float*)d_in[1];
    const float* area  = (const float*)d_in[2];
    const float* h0    = (const float*)d_in[3];
    const float* c0    = (const float*)d_in[4];
    const float* emb   = (const float*)d_in[5];
    const float* W_ih  = (const float*)d_in[6];
    const float* W_hh  = (const float*)d_in[7];
    const float* b_ih  = (const float*)d_in[8];
    const float* b_hh  = (const float*)d_in[9];
    const float* Wv    = (const float*)d_in[10];
    const float* Wh    = (const float*)d_in[11];
    const float* wo    = (const float*)d_in[12];
    const float* W_out = (const float*)d_in[13];
    const float* b_out = (const float*)d_in[14];
    float* out = (float*)d_out;

    char* p = (char*)d_ws;
    auto alloc = [&](size_t bytes) {
        char* q = p;
        p += (bytes + 255) & ~(size_t)255;
        return q;
    };
    u16*   X     = (u16*)alloc((size_t)T_ * B_ * 2 * H_ * 2);        // [2560,1024] bf16
    u16*   WihT  = (u16*)alloc((size_t)4 * H_ * 2 * H_ * 2);         // [2048,1024]
    u16*   WhhT  = (u16*)alloc((size_t)4 * H_ * H_ * 2);             // [2048,512]
    u16*   WvT   = (u16*)alloc((size_t)H_ * H_ * 2);                 // [512,512]
    u16*   WhT   = (u16*)alloc((size_t)H_ * H_ * 2);                 // [512,512]
    u16*   WoutT = (u16*)alloc((size_t)V_ * 2 * H_ * 2);             // [10000,1024]
    u16*   feat  = (u16*)alloc((size_t)B_ * F_ * H_ * 2);            // [6272,512]
    float* Xin   = (float*)alloc((size_t)T_ * B_ * 4 * H_ * 4);      // [2560,2048] f32
    float* Vproj = (float*)alloc((size_t)B_ * F_ * H_ * 4);          // [6272,512] f32
    float* gates = (float*)alloc((size_t)B_ * 4 * H_ * 4);           // [128,2048]
    float* cbuf  = (float*)alloc((size_t)B_ * H_ * 4);
    u16*   hbf   = (u16*)alloc((size_t)B_ * H_ * 2);
    float* ahb   = (float*)alloc((size_t)B_ * H_ * 4);
    u16*   Hcat  = (u16*)alloc((size_t)B_ * T_ * 2 * H_ * 2);        // [2560,1024] bf16

    dim3 tb(32, 8);
    transpose_cvt<<<dim3(4 * H_ / 32, 2 * H_ / 32), tb, 0, stream>>>(W_ih, WihT, 2 * H_, 4 * H_);
    transpose_cvt<<<dim3(4 * H_ / 32, H_ / 32), tb, 0, stream>>>(W_hh, WhhT, H_, 4 * H_);
    transpose_cvt<<<dim3(H_ / 32, H_ / 32), tb, 0, stream>>>(Wv, WvT, H_, H_);
    transpose_cvt<<<dim3(H_ / 32, H_ / 32), tb, 0, stream>>>(Wh, WhT, H_, H_);
    transpose_cvt<<<dim3((V_ + 31) / 32, 2 * H_ / 32), tb, 0, stream>>>(W_out, WoutT, 2 * H_, V_);
    build_x<<<T_ * B_, 256, 0, stream>>>(cap, emb, gf, X);
    feat_cvt<<<(B_ * F_ * H_ + 255) / 256, 256, 0, stream>>>(area, feat);
    init_hc<<<(B_ * H_ + 255) / 256, 256, 0, stream>>>(h0, c0, hbf, cbuf);

    // Xin = X @ W_ih + b_ih + b_hh   [2560,2048]
    gemm_bf16<128, 128><<<dim3(T_ * B_ / 128, 4 * H_ / 128), 256, 0, stream>>>(
        X, 2 * H_, WihT, 2 * H_, Xin, 4 * H_, nullptr, 0, b_ih, b_hh, T_ * B_, 4 * H_, 2 * H_);
    // Vproj = feat @ Wv   [6272,512]
    gemm_bf16<128, 128><<<dim3(B_ * F_ / 128, H_ / 128), 256, 0, stream>>>(
        feat, H_, WvT, H_, Vproj, H_, nullptr, 0, nullptr, nullptr, B_ * F_, H_, H_);

    for (int t = 0; t < T_; ++t) {
        // gates = h @ W_hh + Xin[t]   [128,2048]
        gemm_bf16<64, 64><<<dim3(B_ / 64, 4 * H_ / 64), 256, 0, stream>>>(
            hbf, H_, WhhT, H_, gates, 4 * H_, Xin + (size_t)t * B_ * 4 * H_, 4 * H_,
            nullptr, nullptr, B_, 4 * H_, H_);
        lstm_ew<<<(B_ * H_ + 255) / 256, 256, 0, stream>>>(gates, cbuf, hbf);
        // ah = h @ Wh   [128,512]
        gemm_bf16<64, 64><<<dim3(B_ / 64, H_ / 64), 256, 0, stream>>>(
            hbf, H_, WhT, H_, ahb, H_, nullptr, 0, nullptr, nullptr, B_, H_, H_);
        attention_k<<<B_, 256, 0, stream>>>(Vproj, ahb, wo, area, hbf, Hcat, t);
    }

    // out = Hcat @ W_out + b_out   [2560,10000]
    gemm_bf16<128, 128><<<dim3(T_ * B_ / 128, (V_ + 127) / 128), 256, 0, stream>>>(
        Hcat, 2 * H_, WoutT, 2 * H_, out, V_, nullptr, 0, b_out, nullptr, T_ * B_, V_, 2 * H_);
}

// Round 2
// 1131.078 us; speedup vs baseline: 1.7351x; 1.7351x over previous
//
#include <hip/hip_runtime.h>

#define B_ 128
#define T_ 20
#define V_ 10000
#define H_ 512
#define F_ 49

typedef unsigned short u16;
typedef __attribute__((ext_vector_type(8))) short short8;
typedef __attribute__((ext_vector_type(4))) float floatx4;

#define GLOBAL_AS __attribute__((address_space(1)))
#define LDS_AS    __attribute__((address_space(3)))

__device__ inline void load_lds16(const void* g, void* l) {
    __builtin_amdgcn_global_load_lds((const GLOBAL_AS void*)g, (LDS_AS void*)l, 16, 0, 0);
}

// fp32 -> bf16 round-to-nearest-even
__device__ inline u16 f2b(float v) {
    unsigned u = __builtin_bit_cast(unsigned, v);
    unsigned rounding = 0x7FFFu + ((u >> 16) & 1u);
    return (u16)((u + rounding) >> 16);
}
__device__ inline float b2f(u16 h) {
    unsigned u = ((unsigned)h) << 16;
    return __builtin_bit_cast(float, u);
}
__device__ inline float fast_tanh(float x) {
    return 1.f - 2.f / (__expf(2.f * x) + 1.f);
}
__device__ inline float sigm(float x) { return 1.f / (1.f + __expf(-x)); }

// ---------------- transpose + convert: src[K,N] f32 -> dst[N,K] bf16 ----------------
__global__ __launch_bounds__(256) void transpose_cvt(const float* __restrict__ src,
                                                     u16* __restrict__ dst, int K, int N) {
    __shared__ float tile[32][33];
    int n0 = blockIdx.x * 32, k0 = blockIdx.y * 32;
    int tx = threadIdx.x, ty = threadIdx.y;   // 32 x 8
    #pragma unroll
    for (int i = 0; i < 32; i += 8) {
        int k = k0 + ty + i, n = n0 + tx;
        tile[ty + i][tx] = (k < K && n < N) ? src[(size_t)k * N + n] : 0.f;
    }
    __syncthreads();
    #pragma unroll
    for (int i = 0; i < 32; i += 8) {
        int n = n0 + ty + i, k = k0 + tx;
        if (n < N && k < K) dst[(size_t)n * K + k] = f2b(tile[tx][ty + i]);
    }
}

// ---------------- build X[t*B+b, 0:2H] = [emb[tok], gf[b]] as bf16 ----------------
__global__ __launch_bounds__(256) void build_x(const int* __restrict__ cap,
                                               const float* __restrict__ emb,
                                               const float* __restrict__ gf,
                                               u16* __restrict__ X) {
    int r = blockIdx.x;                 // r = t*128 + b
    int t = r / B_, b = r % B_;
    int tok = cap[b * T_ + t];
    for (int col = threadIdx.x; col < 2 * H_; col += 256) {
        float v = (col < H_) ? emb[(size_t)tok * H_ + col] : gf[(size_t)b * H_ + (col - H_)];
        X[(size_t)r * (2 * H_) + col] = f2b(v);
    }
}

// ---------------- feat[b,f,h] = area[b,h,f] as bf16 ----------------
__global__ __launch_bounds__(256) void feat_cvt(const float* __restrict__ area,
                                                u16* __restrict__ feat) {
    int idx = blockIdx.x * 256 + threadIdx.x;
    if (idx >= B_ * F_ * H_) return;
    int h = idx & (H_ - 1);
    int bf_ = idx >> 9;
    int f = bf_ % F_, b = bf_ / F_;
    feat[idx] = f2b(area[((size_t)b * H_ + h) * F_ + f]);
}

// ---------------- init h (bf16) and c (f32) ----------------
__global__ __launch_bounds__(256) void init_hc(const float* __restrict__ h0,
                                               const float* __restrict__ c0,
                                               u16* __restrict__ hbf, float* __restrict__ c) {
    int i = blockIdx.x * 256 + threadIdx.x;
    if (i < B_ * H_) { hbf[i] = f2b(h0[i]); c[i] = c0[i]; }
}

// ================= fused: gates = h@W_hh + Xin[t]; LSTM elementwise =================
// grid (8, 32), 256 threads. WG: rows m0..m0+15 (b), cols j0..j0+15 (j in [0,512)).
// Wave g computes gate g's 16x16 tile via MFMA with direct-from-global fragments.
__global__ __launch_bounds__(256) void step_gates_lstm(
        const u16* __restrict__ hin, const u16* __restrict__ WhhT,
        const float* __restrict__ Xin_t, float* __restrict__ c,
        u16* __restrict__ hout) {
    __shared__ float gl[4 * 16 * 16];
    const int tid = threadIdx.x, wave = tid >> 6, lane = tid & 63;
    const int lm = lane & 15, q = lane >> 4;
    const int m0 = blockIdx.x * 16, j0 = blockIdx.y * 16;

    const u16* Ap = hin + (size_t)(m0 + lm) * H_ + q * 8;
    const u16* Bp = WhhT + (size_t)(wave * H_ + j0 + lm) * H_ + q * 8;

    floatx4 acc = {0.f, 0.f, 0.f, 0.f};
    #pragma unroll
    for (int kt = 0; kt < 16; ++kt) {
        short8 a = *(const short8*)(Ap + kt * 32);
        short8 b = *(const short8*)(Bp + kt * 32);
        acc = __builtin_amdgcn_mfma_f32_16x16x32_bf16(a, b, acc, 0, 0, 0);
    }
    #pragma unroll
    for (int r = 0; r < 4; ++r)
        gl[wave * 256 + (q * 4 + r) * 16 + lm] = acc[r];
    __syncthreads();

    // LSTM: one element per thread
    const int row = tid >> 4, col = tid & 15;
    const int b = m0 + row, j = j0 + col;
    const float* xt = Xin_t + (size_t)b * (4 * H_);
    float gi = gl[0 * 256 + row * 16 + col] + xt[j];
    float gf = gl[1 * 256 + row * 16 + col] + xt[H_ + j];
    float gg = gl[2 * 256 + row * 16 + col] + xt[2 * H_ + j];
    float go = gl[3 * 256 + row * 16 + col] + xt[3 * H_ + j];
    int idx = b * H_ + j;
    float cn = sigm(gf) * c[idx] + sigm(gi) * fast_tanh(gg);
    c[idx] = cn;
    hout[idx] = f2b(sigm(go) * fast_tanh(cn));
}

// ================= fused attention: ah = h@Wh; scores; softmax; attended; Hcat ======
// grid 128 (one per b), 256 threads.
__global__ __launch_bounds__(256) void step_attn(
        const u16* __restrict__ hbf, const u16* __restrict__ WhT,
        const u16* __restrict__ Vprojb, const float* __restrict__ wo,
        const u16* __restrict__ feat, u16* __restrict__ Hcat, int t) {
    const int b = blockIdx.x, tid = threadIdx.x;
    const int wave = tid >> 6, lane = tid & 63;
    __shared__ float hsh[H_];
    __shared__ float ash[H_];
    __shared__ float wosh[H_];
    __shared__ float sc[64];

    for (int i = tid; i < H_; i += 256) {
        hsh[i] = b2f(hbf[(size_t)b * H_ + i]);
        wosh[i] = wo[i];
    }
    __syncthreads();

    // ah[n] = sum_k h[k] * Wh[k,n] = dot(hsh, WhT[n,:])
    for (int n = tid; n < H_; n += 256) {
        const u16* w = WhT + (size_t)n * H_;
        float s = 0.f;
        #pragma unroll 4
        for (int k = 0; k < H_; k += 8) {
            short8 wv = *(const short8*)(w + k);
            #pragma unroll
            for (int e = 0; e < 8; ++e)
                s += hsh[k + e] * b2f((u16)wv[e]);
        }
        ash[n] = s;
    }
    __syncthreads();

    // scores[f] = sum_h wo[h] * tanh(Vproj[b,f,h] + ah[h]); lane handles 8 contiguous h
    for (int f = wave; f < F_; f += 4) {
        const u16* vp = Vprojb + ((size_t)b * F_ + f) * H_ + lane * 8;
        short8 vv = *(const short8*)vp;
        float s = 0.f;
        #pragma unroll
        for (int e = 0; e < 8; ++e) {
            int h = lane * 8 + e;
            s += wosh[h] * fast_tanh(b2f((u16)vv[e]) + ash[h]);
        }
        #pragma unroll
        for (int off = 32; off; off >>= 1) s += __shfl_xor(s, off);
        if (lane == 0) sc[f] = s;
    }
    __syncthreads();

    // softmax over F=49 (wave 0)
    if (tid < 64) {
        float v = (tid < F_) ? sc[tid] : -1e30f;
        float m = v;
        #pragma unroll
        for (int off = 32; off; off >>= 1) m = fmaxf(m, __shfl_xor(m, off));
        float e = (tid < F_) ? __expf(v - m) : 0.f;
        float sum = e;
        #pragma unroll
        for (int off = 32; off; off >>= 1) sum += __shfl_xor(sum, off);
        if (tid < F_) sc[tid] = e / sum;
    }
    __syncthreads();

    // attended[h] = sum_f feat[b,f,h] * alpha[f]; write Hcat row b*T+t
    const size_t rowo = ((size_t)b * T_ + t) * (2 * H_);
    for (int h = tid; h < H_; h += 256) {
        const u16* fp = feat + (size_t)b * F_ * H_ + h;
        float acc = 0.f;
        #pragma unroll
        for (int f = 0; f < F_; ++f) acc += b2f(fp[f * H_]) * sc[f];
        Hcat[rowo + h] = hbf[(size_t)b * H_ + h];
        Hcat[rowo + H_ + h] = f2b(acc);
    }
}

// ========== m97-style bf16 MFMA GEMM: C[M,N] = A[M,K] @ Bt[N,K]^T (+bias) ==========
// 128x128 tile, BK=32, global_load_lds width-16 staging, unpadded LDS.
template <int WRITE_BF16>
__global__ __launch_bounds__(256) void gemm2(const u16* __restrict__ A, int lda,
                                             const u16* __restrict__ Bt, int ldb,
                                             void* __restrict__ Cout, int ldc,
                                             const float* __restrict__ bias1,
                                             const float* __restrict__ bias2,
                                             int M, int N, int K) {
    __shared__ __align__(16) u16 As[128 * 32];
    __shared__ __align__(16) u16 Bs[128 * 32];
    const int tid = threadIdx.x, wave = tid >> 6, lane = tid & 63;
    const int wr = wave >> 1, wc = wave & 1;
    const int lm = lane & 15, q = lane >> 4;
    const int m0 = blockIdx.x * 128, n0 = blockIdx.y * 128;

    // staging map: byte off within 8 KB tile = issue*4096 + wave*1024 + lane*16
    const int off = wave * 1024 + lane * 16;
    const int r0 = off >> 6;              // row (64 B per 32-elem row)
    const int c0 = (off & 63) >> 1;       // elem col (multiple of 8)

    const u16* gA0 = A + (size_t)(m0 + r0) * lda + c0;
    const u16* gA1 = A + (size_t)(m0 + r0 + 64) * lda + c0;
    int nb0 = n0 + r0;      if (nb0 > N - 1) nb0 = N - 1;
    int nb1 = n0 + r0 + 64; if (nb1 > N - 1) nb1 = N - 1;
    const u16* gB0 = Bt + (size_t)nb0 * ldb + c0;
    const u16* gB1 = Bt + (size_t)nb1 * ldb + c0;
    char* lA0 = (char*)As + wave * 1024;
    char* lA1 = (char*)As + 4096 + wave * 1024;
    char* lB0 = (char*)Bs + wave * 1024;
    char* lB1 = (char*)Bs + 4096 + wave * 1024;

    floatx4 acc[4][4];
    #pragma unroll
    for (int i = 0; i < 4; ++i)
        #pragma unroll
        for (int j = 0; j < 4; ++j) acc[i][j] = floatx4{0.f, 0.f, 0.f, 0.f};

    const int nkt = K >> 5;
    for (int kt = 0; kt < nkt; ++kt) {
        const int ko = kt * 32;
        load_lds16(gA0 + ko, lA0);
        load_lds16(gA1 + ko, lA1);
        load_lds16(gB0 + ko, lB0);
        load_lds16(gB1 + ko, lB1);
        __syncthreads();
        short8 af[4], bf[4];
        #pragma unroll
        for (int i = 0; i < 4; ++i)
            af[i] = *(const short8*)&As[(wr * 64 + i * 16 + lm) * 32 + q * 8];
        #pragma unroll
        for (int j = 0; j < 4; ++j)
            bf[j] = *(const short8*)&Bs[(wc * 64 + j * 16 + lm) * 32 + q * 8];
        #pragma unroll
        for (int i = 0; i < 4; ++i)
            #pragma unroll
            for (int j = 0; j < 4; ++j)
                acc[i][j] = __builtin_amdgcn_mfma_f32_16x16x32_bf16(af[i], bf[j], acc[i][j], 0, 0, 0);
        __syncthreads();
    }

    #pragma unroll
    for (int i = 0; i < 4; ++i) {
        const int row = m0 + wr * 64 + i * 16 + q * 4;
        #pragma unroll
        for (int j = 0; j < 4; ++j) {
            const int col = n0 + wc * 64 + j * 16 + lm;
            if (col < N) {
                #pragma unroll
                for (int r = 0; r < 4; ++r) {
                    float v = acc[i][j][r];
                    if (bias1) v += bias1[col];
                    if (bias2) v += bias2[col];
                    if (WRITE_BF16) ((u16*)Cout)[(size_t)(row + r) * ldc + col] = f2b(v);
                    else            ((float*)Cout)[(size_t)(row + r) * ldc + col] = v;
                }
            }
        }
    }
}

extern "C" void kernel_launch(void* const* d_in, const int* in_sizes, int n_in,
                              void* d_out, int out_size, void* d_ws, size_t ws_size,
                              hipStream_t stream) {
    const int*   cap   = (const int*)d_in[0];
    const float* gf    = (const float*)d_in[1];
    const float* area  = (const float*)d_in[2];
    const float* h0    = (const float*)d_in[3];
    const float* c0    = (const float*)d_in[4];
    const float* emb   = (const float*)d_in[5];
    const float* W_ih  = (const float*)d_in[6];
    const float* W_hh  = (const float*)d_in[7];
    const float* b_ih  = (const float*)d_in[8];
    const float* b_hh  = (const float*)d_in[9];
    const float* Wv    = (const float*)d_in[10];
    const float* Wh    = (const float*)d_in[11];
    const float* wo    = (const float*)d_in[12];
    const float* W_out = (const float*)d_in[13];
    const float* b_out = (const float*)d_in[14];
    float* out = (float*)d_out;

    char* p = (char*)d_ws;
    auto alloc = [&](size_t bytes) {
        char* q = p;
        p += (bytes + 255) & ~(size_t)255;
        return q;
    };
    u16*   X      = (u16*)alloc((size_t)T_ * B_ * 2 * H_ * 2);     // [2560,1024]
    u16*   WihT   = (u16*)alloc((size_t)4 * H_ * 2 * H_ * 2);      // [2048,1024]
    u16*   WhhT   = (u16*)alloc((size_t)4 * H_ * H_ * 2);          // [2048,512]
    u16*   WvT    = (u16*)alloc((size_t)H_ * H_ * 2);              // [512,512]
    u16*   WhT    = (u16*)alloc((size_t)H_ * H_ * 2);              // [512,512]
    u16*   WoutT  = (u16*)alloc((size_t)V_ * 2 * H_ * 2);          // [10000,1024]
    u16*   feat   = (u16*)alloc((size_t)B_ * F_ * H_ * 2);         // [6272,512]
    float* Xin    = (float*)alloc((size_t)T_ * B_ * 4 * H_ * 4);   // [2560,2048] f32
    u16*   Vprojb = (u16*)alloc((size_t)B_ * F_ * H_ * 2);         // [6272,512] bf16
    float* cbuf   = (float*)alloc((size_t)B_ * H_ * 4);
    u16*   hbf0   = (u16*)alloc((size_t)B_ * H_ * 2);
    u16*   hbf1   = (u16*)alloc((size_t)B_ * H_ * 2);
    u16*   Hcat   = (u16*)alloc((size_t)B_ * T_ * 2 * H_ * 2);     // [2560,1024]
    u16* hb[2] = {hbf0, hbf1};

    dim3 tb(32, 8);
    transpose_cvt<<<dim3(4 * H_ / 32, 2 * H_ / 32), tb, 0, stream>>>(W_ih, WihT, 2 * H_, 4 * H_);
    transpose_cvt<<<dim3(4 * H_ / 32, H_ / 32), tb, 0, stream>>>(W_hh, WhhT, H_, 4 * H_);
    transpose_cvt<<<dim3(H_ / 32, H_ / 32), tb, 0, stream>>>(Wv, WvT, H_, H_);
    transpose_cvt<<<dim3(H_ / 32, H_ / 32), tb, 0, stream>>>(Wh, WhT, H_, H_);
    transpose_cvt<<<dim3((V_ + 31) / 32, 2 * H_ / 32), tb, 0, stream>>>(W_out, WoutT, 2 * H_, V_);
    build_x<<<T_ * B_, 256, 0, stream>>>(cap, emb, gf, X);
    feat_cvt<<<(B_ * F_ * H_ + 255) / 256, 256, 0, stream>>>(area, feat);
    init_hc<<<(B_ * H_ + 255) / 256, 256, 0, stream>>>(h0, c0, hbf0, cbuf);

    // Xin = X @ W_ih + b_ih + b_hh   [2560,2048] f32
    gemm2<0><<<dim3(T_ * B_ / 128, 4 * H_ / 128), 256, 0, stream>>>(
        X, 2 * H_, WihT, 2 * H_, Xin, 4 * H_, b_ih, b_hh, T_ * B_, 4 * H_, 2 * H_);
    // Vproj = feat @ Wv  -> bf16 [6272,512]
    gemm2<1><<<dim3(B_ * F_ / 128, H_ / 128), 256, 0, stream>>>(
        feat, H_, WvT, H_, Vprojb, H_, nullptr, nullptr, B_ * F_, H_, H_);

    for (int t = 0; t < T_; ++t) {
        step_gates_lstm<<<dim3(B_ / 16, H_ / 16), 256, 0, stream>>>(
            hb[t & 1], WhhT, Xin + (size_t)t * B_ * 4 * H_, cbuf, hb[(t + 1) & 1]);
        step_attn<<<B_, 256, 0, stream>>>(
            hb[(t + 1) & 1], WhT, Vprojb, wo, feat, Hcat, t);
    }

    // out = Hcat @ W_out + b_out   [2560,10000] f32
    gemm2<0><<<dim3(T_ * B_ / 128, (V_ + 127) / 128), 256, 0, stream>>>(
        Hcat, 2 * H_, WoutT, 2 * H_, out, V_, b_out, nullptr, T_ * B_, V_, 2 * H_);
}